// Round 16
// baseline (144.930 us; speedup 1.0000x reference)
//
#include <hip/hip_runtime.h>

typedef __bf16 bf16;
typedef __attribute__((ext_vector_type(8))) __bf16 bf16x8;
typedef __attribute__((ext_vector_type(4))) __bf16 bf16x4;
typedef __attribute__((ext_vector_type(4))) float f32x4;
typedef __attribute__((ext_vector_type(2))) unsigned long u64x2;

#define S 2048
#define DMODEL 512
#define NH 8
#define DH 64
#define DFF 2048
#define MAXLEN 16384
#define LN_EPS 1e-5f
#define NSP 8
#define CW (S / NSP)
#define BC 64
#define CST 0.18033688f  // (1/8) * log2(e)

__device__ __forceinline__ void gload16(const bf16* g, bf16* l) {
  __builtin_amdgcn_global_load_lds(
      (const __attribute__((address_space(1))) void*)g,
      (__attribute__((address_space(3))) void*)l, 16, 0, 0);
}

// ---------------- 128x128-tile m97-style GEMM (kept for srel) ----------------
// flags: bit0 relu, bit1 bf16 out, bit2 CST on z==0, bit3 skew guard, bit4 V-transpose, bit5 fp8 out
template <int SWAP>
__global__ __launch_bounds__(256) void gemm_k(
    const bf16* __restrict__ A, long sAz, int lda,
    const bf16* __restrict__ B, long sBz, int ldb,
    void* __restrict__ C, long sCz, int ldc,
    const float* __restrict__ bias, long sBiasZ, int flags,
    int M, int N, int K, bf16* __restrict__ Ct)
{
  __shared__ bf16 lsA[128 * 32];
  __shared__ bf16 lsB[128 * 32];
  const int z = blockIdx.z;
  A += (long)z * sAz;
  B += (long)z * sBz;
  const int m0 = blockIdx.y * 128, n0 = blockIdx.x * 128;
  const int tid = threadIdx.x;
  const int lane = tid & 63, w = tid >> 6;
  const int wr = (w >> 1) * 64, wc = (w & 1) * 64;
  const int r15 = lane & 15, kg = lane >> 4;
  const int srow = lane >> 2, scol = (lane & 3) * 8;

  const bf16* Ag0 = A + (long)(m0 + 32 * w + srow) * lda + scol;
  const bf16* Ag1 = Ag0 + 16 * lda;
  const bf16* Bg0 = B + (long)(n0 + 32 * w + srow) * ldb + scol;
  const bf16* Bg1 = Bg0 + 16 * ldb;
  bf16* La0 = &lsA[(32 * w + srow) * 32 + scol];
  bf16* La1 = La0 + 16 * 32;
  bf16* Lb0 = &lsB[(32 * w + srow) * 32 + scol];
  bf16* Lb1 = Lb0 + 16 * 32;

  f32x4 acc[4][4] = {};
  for (int k0 = 0; k0 < K; k0 += 32) {
    gload16(Ag0 + k0, La0);
    gload16(Ag1 + k0, La1);
    gload16(Bg0 + k0, Lb0);
    gload16(Bg1 + k0, Lb1);
    __syncthreads();
    bf16x8 af[4], bfr[4];
#pragma unroll
    for (int mi = 0; mi < 4; ++mi) af[mi] = *(const bf16x8*)&lsA[(wr + mi * 16 + r15) * 32 + kg * 8];
#pragma unroll
    for (int ni = 0; ni < 4; ++ni) bfr[ni] = *(const bf16x8*)&lsB[(wc + ni * 16 + r15) * 32 + kg * 8];
    __builtin_amdgcn_s_setprio(1);
#pragma unroll
    for (int mi = 0; mi < 4; ++mi)
#pragma unroll
      for (int ni = 0; ni < 4; ++ni) {
        if (SWAP)
          acc[mi][ni] = __builtin_amdgcn_mfma_f32_16x16x32_bf16(bfr[ni], af[mi], acc[mi][ni], 0, 0, 0);
        else
          acc[mi][ni] = __builtin_amdgcn_mfma_f32_16x16x32_bf16(af[mi], bfr[ni], acc[mi][ni], 0, 0, 0);
      }
    __builtin_amdgcn_s_setprio(0);
    __syncthreads();
  }
  const float* bz = bias ? bias + (long)z * sBiasZ : nullptr;
  const float scl = ((flags & 4) && z == 0) ? CST : 1.f;

  if (SWAP) {
#pragma unroll
    for (int mi = 0; mi < 4; ++mi) {
      int row = m0 + wr + mi * 16 + r15;
#pragma unroll
      for (int ni = 0; ni < 4; ++ni) {
        int col0 = n0 + wc + ni * 16 + 4 * kg;
        float v[4];
#pragma unroll
        for (int r = 0; r < 4; ++r) {
          float bv = bz ? bz[col0 + r] : 0.f;
          v[r] = (acc[mi][ni][r] + bv) * scl;
          if (flags & 1) v[r] = fmaxf(v[r], 0.f);
        }
        long off = (long)z * sCz + (long)row * ldc + col0;
        if (flags & 2) {
          bf16x4 o = { (bf16)v[0], (bf16)v[1], (bf16)v[2], (bf16)v[3] };
          *(bf16x4*)&((bf16*)C)[off] = o;
        } else {
          f32x4 o = { v[0], v[1], v[2], v[3] };
          *(f32x4*)&((float*)C)[off] = o;
        }
      }
    }
  } else {
#pragma unroll
    for (int mi = 0; mi < 4; ++mi)
#pragma unroll
      for (int ni = 0; ni < 4; ++ni) {
        int col = n0 + wc + ni * 16 + r15;
        float bv = bz ? bz[col] : 0.f;
        float v[4];
#pragma unroll
        for (int r = 0; r < 4; ++r) {
          v[r] = (acc[mi][ni][r] + bv) * scl;
          if (flags & 1) v[r] = fmaxf(v[r], 0.f);
        }
        int rowb = m0 + wr + mi * 16 + kg * 4;
        if ((flags & 16) && z == 2) {
          bf16x4 o = { (bf16)v[0], (bf16)v[1], (bf16)v[2], (bf16)v[3] };
          *(bf16x4*)&Ct[(long)col * M + rowb] = o;
        } else {
#pragma unroll
          for (int r = 0; r < 4; ++r) {
            int row = rowb + r;
            if ((flags & 8) && row == 0 && col < N - 1) continue;
            if (flags & 32) {
              int pk = __builtin_amdgcn_cvt_pk_fp8_f32(v[r], v[r], 0, false);
              ((unsigned char*)C)[(long)z * sCz + (long)row * ldc + col] = (unsigned char)(pk & 0xff);
            } else if (flags & 2) {
              ((bf16*)C)[(long)z * sCz + (long)row * ldc + col] = (bf16)v[r];
            } else {
              ((float*)C)[(long)z * sCz + (long)row * ldc + col] = v[r];
            }
          }
        }
      }
  }
}

// ---------------- 64x64-tile m97-style GEMM (high block count for small shapes) ----------------
// 4 waves, each 32x32 (acc[2][2]); LDS 8KB; same flag semantics (subset).
template <int SWAP>
__global__ __launch_bounds__(256) void gemm64_k(
    const bf16* __restrict__ A, long sAz, int lda,
    const bf16* __restrict__ B, long sBz, int ldb,
    void* __restrict__ C, long sCz, int ldc,
    const float* __restrict__ bias, long sBiasZ, int flags,
    int M, int N, int K, bf16* __restrict__ Ct)
{
  __shared__ bf16 lsA[64 * 32];
  __shared__ bf16 lsB[64 * 32];
  const int z = blockIdx.z;
  A += (long)z * sAz;
  B += (long)z * sBz;
  const int m0 = blockIdx.y * 64, n0 = blockIdx.x * 64;
  const int tid = threadIdx.x;
  const int lane = tid & 63, w = tid >> 6;
  const int wr = (w >> 1) * 32, wc = (w & 1) * 32;
  const int r15 = lane & 15, kg = lane >> 4;
  const int srow = tid >> 2, scol = (tid & 3) * 8;

  const bf16* Ag = A + (long)(m0 + srow) * lda + scol;
  const bf16* Bg = B + (long)(n0 + srow) * ldb + scol;
  bf16* La = &lsA[srow * 32 + scol];
  bf16* Lb = &lsB[srow * 32 + scol];

  f32x4 acc[2][2] = {};
  for (int k0 = 0; k0 < K; k0 += 32) {
    gload16(Ag + k0, La);
    gload16(Bg + k0, Lb);
    __syncthreads();
    bf16x8 af[2], bfr[2];
#pragma unroll
    for (int mi = 0; mi < 2; ++mi) af[mi] = *(const bf16x8*)&lsA[(wr + mi * 16 + r15) * 32 + kg * 8];
#pragma unroll
    for (int ni = 0; ni < 2; ++ni) bfr[ni] = *(const bf16x8*)&lsB[(wc + ni * 16 + r15) * 32 + kg * 8];
    __builtin_amdgcn_s_setprio(1);
#pragma unroll
    for (int mi = 0; mi < 2; ++mi)
#pragma unroll
      for (int ni = 0; ni < 2; ++ni) {
        if (SWAP)
          acc[mi][ni] = __builtin_amdgcn_mfma_f32_16x16x32_bf16(bfr[ni], af[mi], acc[mi][ni], 0, 0, 0);
        else
          acc[mi][ni] = __builtin_amdgcn_mfma_f32_16x16x32_bf16(af[mi], bfr[ni], acc[mi][ni], 0, 0, 0);
      }
    __builtin_amdgcn_s_setprio(0);
    __syncthreads();
  }
  const float* bz = bias ? bias + (long)z * sBiasZ : nullptr;
  const float scl = ((flags & 4) && z == 0) ? CST : 1.f;

  if (SWAP) {
#pragma unroll
    for (int mi = 0; mi < 2; ++mi) {
      int row = m0 + wr + mi * 16 + r15;
#pragma unroll
      for (int ni = 0; ni < 2; ++ni) {
        int col0 = n0 + wc + ni * 16 + 4 * kg;
        float v[4];
#pragma unroll
        for (int r = 0; r < 4; ++r) {
          float bv = bz ? bz[col0 + r] : 0.f;
          v[r] = (acc[mi][ni][r] + bv) * scl;
          if (flags & 1) v[r] = fmaxf(v[r], 0.f);
        }
        long off = (long)z * sCz + (long)row * ldc + col0;
        if (flags & 2) {
          bf16x4 o = { (bf16)v[0], (bf16)v[1], (bf16)v[2], (bf16)v[3] };
          *(bf16x4*)&((bf16*)C)[off] = o;
        } else {
          f32x4 o = { v[0], v[1], v[2], v[3] };
          *(f32x4*)&((float*)C)[off] = o;
        }
      }
    }
  } else {
#pragma unroll
    for (int mi = 0; mi < 2; ++mi)
#pragma unroll
      for (int ni = 0; ni < 2; ++ni) {
        int col = n0 + wc + ni * 16 + r15;
        float bv = bz ? bz[col] : 0.f;
        float v[4];
#pragma unroll
        for (int r = 0; r < 4; ++r) {
          v[r] = (acc[mi][ni][r] + bv) * scl;
          if (flags & 1) v[r] = fmaxf(v[r], 0.f);
        }
        int rowb = m0 + wr + mi * 16 + kg * 4;
        if ((flags & 16) && z == 2) {
          bf16x4 o = { (bf16)v[0], (bf16)v[1], (bf16)v[2], (bf16)v[3] };
          *(bf16x4*)&Ct[(long)col * M + rowb] = o;
        } else {
#pragma unroll
          for (int r = 0; r < 4; ++r) {
            int row = rowb + r;
            if (flags & 2) ((bf16*)C)[(long)z * sCz + (long)row * ldc + col] = (bf16)v[r];
            else           ((float*)C)[(long)z * sCz + (long)row * ldc + col] = v[r];
          }
        }
      }
  }
}

// ---------------- fused prep: x0 conv / Er conv / zdiag(fp8) / bias pack / weight transposes ----------------
__global__ __launch_bounds__(256) void prep_k(
    const float* __restrict__ src, const float* __restrict__ Er,
    const float* __restrict__ Wq, const float* __restrict__ Wk, const float* __restrict__ Wv,
    const float* __restrict__ W1, const float* __restrict__ W2,
    const float* __restrict__ bq, const float* __restrict__ bk, const float* __restrict__ bv,
    bf16* __restrict__ x0b, bf16* __restrict__ erS, unsigned char* __restrict__ srel,
    float* __restrict__ bqkv,
    bf16* __restrict__ wqkvT, bf16* __restrict__ w1T, bf16* __restrict__ w2T)
{
  __shared__ float t[32][33];
  const int bid = blockIdx.x, tid = threadIdx.x;
  if (bid < 4096) {
    long i = (long)bid * 256 + tid;
    int s2 = (int)(i >> 9), d = (int)(i & 511);
    x0b[i] = (bf16)src[(long)s2 * (2 * DMODEL) + d];
    return;
  }
  int b1_ = bid - 4096;
  if (b1_ < 512) {
    long i = (long)b1_ * 256 + tid;
    erS[i] = (bf16)Er[(long)(MAXLEN - S) * DH + i];
    return;
  }
  b1_ -= 512;
  if (b1_ < 64) {
    int i = b1_ * 256 + tid;
    if (i < NH * (S - 1)) {
      int h = i / (S - 1), rg = i - h * (S - 1);
      srel[(long)h * S * S + (long)rg * (S + 1) + 1] = 0;  // fp8 zero
    }
    return;
  }
  b1_ -= 64;
  if (b1_ < 6) {
    int ti = b1_ * 256 + tid;
    bqkv[ti] = ti < 512 ? bq[ti] : (ti < 1024 ? bk[ti - 512] : bv[ti - 1024]);
    return;
  }
  b1_ -= 6;
  const float* in;
  bf16* out;
  int R, Cn, bx, by;
  if (b1_ < 768) {
    int z = b1_ >> 8, rem = b1_ & 255;
    in = z == 0 ? Wq : (z == 1 ? Wk : Wv);
    out = wqkvT + (long)z * DMODEL * DMODEL;
    R = DMODEL; Cn = DMODEL; bx = rem & 15; by = rem >> 4;
  } else if (b1_ < 768 + 1024) {
    int rem = b1_ - 768;
    in = W1; out = w1T; R = DMODEL; Cn = DFF; bx = rem & 63; by = rem >> 6;
  } else {
    int rem = b1_ - 1792;
    in = W2; out = w2T; R = DFF; Cn = DMODEL; bx = rem & 15; by = rem >> 4;
  }
  int c0 = bx * 32, r0 = by * 32, tx = tid & 31, ty = tid >> 5;
#pragma unroll
  for (int i = 0; i < 32; i += 8) t[ty + i][tx] = in[(long)(r0 + ty + i) * Cn + c0 + tx];
  __syncthreads();
#pragma unroll
  for (int i = 0; i < 32; i += 8) out[(long)(c0 + ty + i) * R + r0 + tx] = (bf16)t[tx][ty + i];
}

// ---------------- fused attention v9 (r15, fp8 srel tile; measured best) ----------------
__global__ __launch_bounds__(256, 5) void attn_k(
    const bf16* __restrict__ qg, const bf16* __restrict__ kgl, const bf16* __restrict__ vtg,
    const unsigned char* __restrict__ srel,
    bf16* __restrict__ pO, float* __restrict__ pM, float* __restrict__ pL)
{
  __shared__ bf16 Kl[64 * 72];            // K tile [c][k]
  __shared__ bf16 Vl[64 * 72];            // V^T tile [d][c]
  __shared__ unsigned char SPb[64 * 72];  // fp8 Srel tile [q][c]
  __shared__ bf16 Pl[4][16 * 72];         // per-wave P
  const int bx = blockIdx.x, h = blockIdx.y;
  const int rb = bx >> 3, sp = bx & 7;
  const int r0 = rb * 64;
  const int cb = sp * CW;
  const int tid = threadIdx.x, lane = tid & 63, w = tid >> 6;
  const int r15 = lane & 15, g = lane >> 4;
  const long hb = (long)h * S * S;

  bf16x8 qf0, qf1;
  {
    const bf16* qrow = qg + (long)(r0 + w * 16 + r15) * DMODEL + h * DH;
    qf0 = *(const bf16x8*)&qrow[g * 8];
    qf1 = *(const bf16x8*)&qrow[32 + g * 8];
  }
  f32x4 Oacc[4] = {};
  float m2 = -1e30f, l2 = 0.f;

  const int myrow = w * 16 + r15;
  const int rg = r0 + myrow;

  const int kRow = tid >> 3, kCh = (tid & 7) * 8;
  const int sRow = tid >> 2, sCh = (tid & 3) * 16;
  bf16x8 kf0, kf1, vf0, vf1;
  u64x2 sf;

  auto LOADR = [&](int c0) {
    kf0 = *(const bf16x8*)&kgl[(long)(c0 + kRow) * DMODEL + h * DH + kCh];
    kf1 = *(const bf16x8*)&kgl[(long)(c0 + kRow + 32) * DMODEL + h * DH + kCh];
    vf0 = *(const bf16x8*)&vtg[(long)(h * DH + kRow) * S + c0 + kCh];
    vf1 = *(const bf16x8*)&vtg[(long)(h * DH + kRow + 32) * S + c0 + kCh];
    sf = *(const u64x2*)&srel[hb + (long)(r0 + sRow) * S + c0 + sCh];
  };
  auto STORE = [&]() {
    *(bf16x8*)&Kl[kRow * 72 + kCh] = kf0;
    *(bf16x8*)&Kl[(kRow + 32) * 72 + kCh] = kf1;
    *(bf16x8*)&Vl[kRow * 72 + kCh] = vf0;
    *(bf16x8*)&Vl[(kRow + 32) * 72 + kCh] = vf1;
    *(unsigned long*)&SPb[sRow * 72 + sCh] = sf.x;
    *(unsigned long*)&SPb[sRow * 72 + sCh + 8] = sf.y;
  };

  LOADR(cb);
#pragma unroll
  for (int t = 0; t < CW / BC; ++t) {
    __syncthreads();
    STORE();
    if (t + 1 < CW / BC) LOADR(cb + (t + 1) * BC);
    __syncthreads();

    f32x4 sc[4];
    __builtin_amdgcn_s_setprio(1);
#pragma unroll
    for (int ni = 0; ni < 4; ++ni) {
      bf16x8 k0f = *(const bf16x8*)&Kl[(ni * 16 + r15) * 72 + g * 8];
      bf16x8 k1f = *(const bf16x8*)&Kl[(ni * 16 + r15) * 72 + 32 + g * 8];
      f32x4 a = {};
      a = __builtin_amdgcn_mfma_f32_16x16x32_bf16(k0f, qf0, a, 0, 0, 0);
      a = __builtin_amdgcn_mfma_f32_16x16x32_bf16(k1f, qf1, a, 0, 0, 0);
      sc[ni] = a;
    }
    __builtin_amdgcn_s_setprio(0);

    const unsigned char* Sw = &SPb[myrow * 72];
#pragma unroll
    for (int ni = 0; ni < 4; ++ni) {
      unsigned int u = *(const unsigned int*)&Sw[ni * 16 + 4 * g];
      sc[ni][0] += __builtin_amdgcn_cvt_f32_fp8(u, 0);
      sc[ni][1] += __builtin_amdgcn_cvt_f32_fp8(u, 1);
      sc[ni][2] += __builtin_amdgcn_cvt_f32_fp8(u, 2);
      sc[ni][3] += __builtin_amdgcn_cvt_f32_fp8(u, 3);
    }

    float tmax = sc[0][0];
#pragma unroll
    for (int ni = 0; ni < 4; ++ni)
#pragma unroll
      for (int r = 0; r < 4; ++r) tmax = fmaxf(tmax, sc[ni][r]);
    tmax = fmaxf(tmax, __shfl_xor(tmax, 16));
    tmax = fmaxf(tmax, __shfl_xor(tmax, 32));

    float mn = fmaxf(m2, tmax);
    float al = exp2f(m2 - mn);
    m2 = mn;
    float tsum = 0.f;
#pragma unroll
    for (int ni = 0; ni < 4; ++ni)
#pragma unroll
      for (int r = 0; r < 4; ++r) {
        float p = exp2f(sc[ni][r] - m2);
        sc[ni][r] = p;
        tsum += p;
      }
    tsum += __shfl_xor(tsum, 16);
    tsum += __shfl_xor(tsum, 32);
    l2 = l2 * al + tsum;

#pragma unroll
    for (int no = 0; no < 4; ++no)
#pragma unroll
      for (int r = 0; r < 4; ++r) Oacc[no][r] *= al;

    bf16* Pw = Pl[w];
#pragma unroll
    for (int ni = 0; ni < 4; ++ni) {
      bf16x4 pv = { (bf16)sc[ni][0], (bf16)sc[ni][1], (bf16)sc[ni][2], (bf16)sc[ni][3] };
      *(bf16x4*)&Pw[r15 * 72 + ni * 16 + 4 * g] = pv;
    }

    __builtin_amdgcn_s_setprio(1);
#pragma unroll
    for (int kc = 0; kc < 2; ++kc) {
      bf16x8 pf = *(const bf16x8*)&Pw[r15 * 72 + kc * 32 + g * 8];
#pragma unroll
      for (int no = 0; no < 4; ++no) {
        bf16x8 av = *(const bf16x8*)&Vl[(no * 16 + r15) * 72 + kc * 32 + g * 8];
        Oacc[no] = __builtin_amdgcn_mfma_f32_16x16x32_bf16(av, pf, Oacc[no], 0, 0, 0);
      }
    }
    __builtin_amdgcn_s_setprio(0);
  }

  const long ob = ((long)sp * NH + h) * S * DH;
  const long qrow_g = r0 + w * 16 + r15;
#pragma unroll
  for (int no = 0; no < 4; ++no) {
    bf16x4 ov = { (bf16)Oacc[no][0], (bf16)Oacc[no][1], (bf16)Oacc[no][2], (bf16)Oacc[no][3] };
    *(bf16x4*)&pO[ob + qrow_g * DH + no * 16 + 4 * g] = ov;
  }
  if (g == 0) {
    const long sb = ((long)sp * NH + h) * S;
    pM[sb + rg] = m2;
    pL[sb + rg] = l2;
  }
}

// ---------------- layernorm helpers ----------------
__device__ __forceinline__ float blk_sum(float v, float* red) {
  for (int o = 32; o; o >>= 1) v += __shfl_xor(v, o);
  int tid = threadIdx.x;
  if ((tid & 63) == 0) red[tid >> 6] = v;
  __syncthreads();
  v = red[0] + red[1] + red[2] + red[3];
  __syncthreads();
  return v;
}

// ---------------- fused merge + LN1 ----------------
__global__ __launch_bounds__(256) void lnm1_k(
    const float* __restrict__ src, const bf16* __restrict__ pO,
    const float* __restrict__ pM, const float* __restrict__ pL,
    const float* __restrict__ g, const float* __restrict__ be, bf16* __restrict__ y)
{
  __shared__ float red[4];
  const int s2 = blockIdx.x, tid = threadIdx.x;
  float sa[2];
#pragma unroll
  for (int half = 0; half < 2; ++half) {
    int col = tid + half * 256;
    int h = col >> 6, d = col & 63;
    long i0 = (long)h * S + s2;
    float mm = -1e30f, ms[NSP];
#pragma unroll
    for (int s = 0; s < NSP; ++s) { ms[s] = pM[(long)s * NH * S + i0]; mm = fmaxf(mm, ms[s]); }
    float num = 0.f, den = 0.f;
#pragma unroll
    for (int s = 0; s < NSP; ++s) {
      float e = exp2f(ms[s] - mm);
      den += pL[(long)s * NH * S + i0] * e;
      num += (float)pO[(long)s * NH * S * DH + i0 * DH + d] * e;
    }
    sa[half] = num / den;
  }
#pragma unroll
  for (int b = 0; b < 2; ++b) {
    const float* xs = src + (long)s2 * (2 * DMODEL) + b * DMODEL;
    float a0 = xs[tid] + sa[0];
    float a1 = xs[tid + 256] + sa[1];
    float sum = blk_sum(a0 + a1, red);
    float sq  = blk_sum(a0 * a0 + a1 * a1, red);
    float mu = sum * (1.f / DMODEL);
    float var = sq * (1.f / DMODEL) - mu * mu;
    float rs = rsqrtf(var + LN_EPS);
    long ro = ((long)b * S + s2) * DMODEL;
    y[ro + tid]       = (bf16)((a0 - mu) * rs * g[tid] + be[tid]);
    y[ro + tid + 256] = (bf16)((a1 - mu) * rs * g[tid + 256] + be[tid + 256]);
  }
}

// out = LN( y + sum_4(pFF) + b2 ) ; pFF are bf16 split-K partials
__global__ __launch_bounds__(256) void ln2_k(
    const bf16* __restrict__ y, const bf16* __restrict__ pFF, long pStride,
    const float* __restrict__ b2,
    const float* __restrict__ g, const float* __restrict__ be, float* __restrict__ out)
{
  __shared__ float red[4];
  const int row = blockIdx.x;
  const int b = row >> 11, s2 = row & 2047;
  const int tid = threadIdx.x;
  long i0 = (long)row * DMODEL + tid;
  long i1 = i0 + 256;
  float f0 = (float)pFF[i0] + (float)pFF[i0 + pStride] + (float)pFF[i0 + 2 * pStride] +
             (float)pFF[i0 + 3 * pStride] + b2[tid];
  float f1 = (float)pFF[i1] + (float)pFF[i1 + pStride] + (float)pFF[i1 + 2 * pStride] +
             (float)pFF[i1 + 3 * pStride] + b2[tid + 256];
  float a0 = (float)y[i0] + f0;
  float a1 = (float)y[i1] + f1;
  float sum = blk_sum(a0 + a1, red);
  float sq  = blk_sum(a0 * a0 + a1 * a1, red);
  float mu = sum * (1.f / DMODEL);
  float var = sq * (1.f / DMODEL) - mu * mu;
  float rs = rsqrtf(var + LN_EPS);
  float* o = out + (long)s2 * (2 * DMODEL) + b * DMODEL;
  o[tid]       = (a0 - mu) * rs * g[tid] + be[tid];
  o[tid + 256] = (a1 - mu) * rs * g[tid + 256] + be[tid + 256];
}

// ---------------- host launch ----------------
extern "C" void kernel_launch(void* const* d_in, const int* in_sizes, int n_in,
                              void* d_out, int out_size, void* d_ws, size_t ws_size,
                              hipStream_t stream)
{
  const float* src = (const float*)d_in[0];
  const float* Wq  = (const float*)d_in[1];
  const float* bq  = (const float*)d_in[2];
  const float* Wk  = (const float*)d_in[3];
  const float* bk  = (const float*)d_in[4];
  const float* Wv  = (const float*)d_in[5];
  const float* bv  = (const float*)d_in[6];
  const float* Er  = (const float*)d_in[7];
  const float* W1  = (const float*)d_in[8];
  const float* b1  = (const float*)d_in[9];
  const float* W2  = (const float*)d_in[10];
  const float* b2  = (const float*)d_in[11];
  const float* g1  = (const float*)d_in[12];
  const float* be1 = (const float*)d_in[13];
  const float* g2  = (const float*)d_in[14];
  const float* be2 = (const float*)d_in[15];

  char* wp = (char*)d_ws;
  auto alloc = [&](size_t bytes) { char* p = wp; wp += (bytes + 255) & ~(size_t)255; return p; };

  bf16* x0b   = (bf16*)alloc((size_t)S * DMODEL * 2);
  bf16* wqkvT = (bf16*)alloc((size_t)3 * DMODEL * DMODEL * 2);
  float* bqkv = (float*)alloc((size_t)3 * DMODEL * 4);
  bf16* w1T   = (bf16*)alloc((size_t)DFF * DMODEL * 2);
  bf16* w2T   = (bf16*)alloc((size_t)DMODEL * DFF * 2);
  bf16* erS   = (bf16*)alloc((size_t)S * DH * 2);
  bf16* qkvb  = (bf16*)alloc((size_t)3 * S * DMODEL * 2);
  bf16* vt    = (bf16*)alloc((size_t)DMODEL * S * 2);
  unsigned char* srel = (unsigned char*)alloc((size_t)NH * S * S);
  bf16* pO    = (bf16*)alloc((size_t)NSP * NH * S * DH * 2);
  float* pM   = (float*)alloc((size_t)NSP * NH * S * 4);
  float* pL   = (float*)alloc((size_t)NSP * NH * S * 4);
  bf16* yb    = (bf16*)alloc((size_t)2 * S * DMODEL * 2);
  bf16* h1    = (bf16*)alloc((size_t)2 * S * DFF * 2);
  bf16* pFF   = (bf16*)alloc((size_t)4 * 2 * S * DMODEL * 2);

  const long MN2 = (long)2 * S * DMODEL;

  // all prep in one launch
  prep_k<<<7494, 256, 0, stream>>>(src, Er, Wq, Wk, Wv, W1, W2, bq, bk, bv,
                                   x0b, erS, srel, bqkv, wqkvT, w1T, w2T);

  // QKV (batch 0 only), 64x64 tiles -> 768 blocks (was 192); z==0 (Q) pre-scaled; V transposed
  gemm64_k<0><<<dim3(DMODEL / 64, S / 64, 3), 256, 0, stream>>>(
      x0b, 0, DMODEL, wqkvT, (long)DMODEL * DMODEL, DMODEL,
      qkvb, (long)S * DMODEL, DMODEL, bqkv, DMODEL, 2 | 4 | 16, S, DMODEL, DMODEL, vt);

  const bf16* qb = qkvb;
  const bf16* kb = qkvb + (long)S * DMODEL;

  // Srel materialized directly as fp8 (128x128 tiles, write-bound)
  gemm_k<0><<<dim3(16, 16, 8), 256, 0, stream>>>(
      qb, DH, DMODEL, erS, 0, DH, (void*)(srel - (S - 1)), (long)S * S, S + 1,
      nullptr, 0, 8 | 32, S, S, DH, nullptr);

  // fused attention (r15 best)
  attn_k<<<dim3(32 * NSP, NH), 256, 0, stream>>>(qb, kb, vt, srel, pO, pM, pL);

  // fused merge + LN1 -> y (bf16)
  lnm1_k<<<S, 256, 0, stream>>>(src, pO, pM, pL, g1, be1, yb);

  // FFN1: 64x64 tiles -> 2048 blocks (was 512)
  gemm64_k<1><<<dim3(DFF / 64, (2 * S) / 64, 1), 256, 0, stream>>>(
      yb, 0, DMODEL, w1T, 0, DMODEL, h1, 0, DFF, b1, 0, 3, 2 * S, DFF, DMODEL, nullptr);

  // FFN2 split-K=4: 64x64 tiles -> 2048 blocks (was 512)
  gemm64_k<1><<<dim3(DMODEL / 64, (2 * S) / 64, 4), 256, 0, stream>>>(
      h1, 512, DFF, w2T, 512, DFF, pFF, MN2, DMODEL, nullptr, 0, 2, 2 * S, DMODEL, 512, nullptr);

  // LN2 (+partial-sum +b2) -> out
  ln2_k<<<2 * S, 256, 0, stream>>>(yb, pFF, MN2, b2, g2, be2, (float*)d_out);
}

// Round 17
// 136.211 us; speedup vs baseline: 1.0640x; 1.0640x over previous
//
#include <hip/hip_runtime.h>

typedef __bf16 bf16;
typedef __attribute__((ext_vector_type(8))) __bf16 bf16x8;
typedef __attribute__((ext_vector_type(4))) __bf16 bf16x4;
typedef __attribute__((ext_vector_type(4))) float f32x4;
typedef __attribute__((ext_vector_type(2))) unsigned long u64x2;

#define S 2048
#define DMODEL 512
#define NH 8
#define DH 64
#define DFF 2048
#define MAXLEN 16384
#define LN_EPS 1e-5f
#define NSP 8
#define CW (S / NSP)
#define BC 64
#define CST 0.18033688f  // (1/8) * log2(e)

__device__ __forceinline__ void gload16(const bf16* g, bf16* l) {
  __builtin_amdgcn_global_load_lds(
      (const __attribute__((address_space(1))) void*)g,
      (__attribute__((address_space(3))) void*)l, 16, 0, 0);
}

// ---------------- 128x128-tile m97-style GEMM ----------------
// flags: bit0 relu, bit1 bf16 out, bit2 CST on z==0, bit3 skew guard, bit4 V-transpose, bit5 fp8 out
template <int SWAP>
__global__ __launch_bounds__(256) void gemm_k(
    const bf16* __restrict__ A, long sAz, int lda,
    const bf16* __restrict__ B, long sBz, int ldb,
    void* __restrict__ C, long sCz, int ldc,
    const float* __restrict__ bias, long sBiasZ, int flags,
    int M, int N, int K, bf16* __restrict__ Ct)
{
  __shared__ bf16 lsA[128 * 32];
  __shared__ bf16 lsB[128 * 32];
  const int z = blockIdx.z;
  A += (long)z * sAz;
  B += (long)z * sBz;
  const int m0 = blockIdx.y * 128, n0 = blockIdx.x * 128;
  const int tid = threadIdx.x;
  const int lane = tid & 63, w = tid >> 6;
  const int wr = (w >> 1) * 64, wc = (w & 1) * 64;
  const int r15 = lane & 15, kg = lane >> 4;
  const int srow = lane >> 2, scol = (lane & 3) * 8;

  const bf16* Ag0 = A + (long)(m0 + 32 * w + srow) * lda + scol;
  const bf16* Ag1 = Ag0 + 16 * lda;
  const bf16* Bg0 = B + (long)(n0 + 32 * w + srow) * ldb + scol;
  const bf16* Bg1 = Bg0 + 16 * ldb;
  bf16* La0 = &lsA[(32 * w + srow) * 32 + scol];
  bf16* La1 = La0 + 16 * 32;
  bf16* Lb0 = &lsB[(32 * w + srow) * 32 + scol];
  bf16* Lb1 = Lb0 + 16 * 32;

  f32x4 acc[4][4] = {};
  for (int k0 = 0; k0 < K; k0 += 32) {
    gload16(Ag0 + k0, La0);
    gload16(Ag1 + k0, La1);
    gload16(Bg0 + k0, Lb0);
    gload16(Bg1 + k0, Lb1);
    __syncthreads();
    bf16x8 af[4], bfr[4];
#pragma unroll
    for (int mi = 0; mi < 4; ++mi) af[mi] = *(const bf16x8*)&lsA[(wr + mi * 16 + r15) * 32 + kg * 8];
#pragma unroll
    for (int ni = 0; ni < 4; ++ni) bfr[ni] = *(const bf16x8*)&lsB[(wc + ni * 16 + r15) * 32 + kg * 8];
    __builtin_amdgcn_s_setprio(1);
#pragma unroll
    for (int mi = 0; mi < 4; ++mi)
#pragma unroll
      for (int ni = 0; ni < 4; ++ni) {
        if (SWAP)
          acc[mi][ni] = __builtin_amdgcn_mfma_f32_16x16x32_bf16(bfr[ni], af[mi], acc[mi][ni], 0, 0, 0);
        else
          acc[mi][ni] = __builtin_amdgcn_mfma_f32_16x16x32_bf16(af[mi], bfr[ni], acc[mi][ni], 0, 0, 0);
      }
    __builtin_amdgcn_s_setprio(0);
    __syncthreads();
  }
  const float* bz = bias ? bias + (long)z * sBiasZ : nullptr;
  const float scl = ((flags & 4) && z == 0) ? CST : 1.f;

  if (SWAP) {
#pragma unroll
    for (int mi = 0; mi < 4; ++mi) {
      int row = m0 + wr + mi * 16 + r15;
#pragma unroll
      for (int ni = 0; ni < 4; ++ni) {
        int col0 = n0 + wc + ni * 16 + 4 * kg;
        float v[4];
#pragma unroll
        for (int r = 0; r < 4; ++r) {
          float bv = bz ? bz[col0 + r] : 0.f;
          v[r] = (acc[mi][ni][r] + bv) * scl;
          if (flags & 1) v[r] = fmaxf(v[r], 0.f);
        }
        long off = (long)z * sCz + (long)row * ldc + col0;
        if (flags & 2) {
          bf16x4 o = { (bf16)v[0], (bf16)v[1], (bf16)v[2], (bf16)v[3] };
          *(bf16x4*)&((bf16*)C)[off] = o;
        } else {
          f32x4 o = { v[0], v[1], v[2], v[3] };
          *(f32x4*)&((float*)C)[off] = o;
        }
      }
    }
  } else {
#pragma unroll
    for (int mi = 0; mi < 4; ++mi)
#pragma unroll
      for (int ni = 0; ni < 4; ++ni) {
        int col = n0 + wc + ni * 16 + r15;
        float bv = bz ? bz[col] : 0.f;
        float v[4];
#pragma unroll
        for (int r = 0; r < 4; ++r) {
          v[r] = (acc[mi][ni][r] + bv) * scl;
          if (flags & 1) v[r] = fmaxf(v[r], 0.f);
        }
        int rowb = m0 + wr + mi * 16 + kg * 4;
        if ((flags & 16) && z == 2) {
          bf16x4 o = { (bf16)v[0], (bf16)v[1], (bf16)v[2], (bf16)v[3] };
          *(bf16x4*)&Ct[(long)col * M + rowb] = o;
        } else {
#pragma unroll
          for (int r = 0; r < 4; ++r) {
            int row = rowb + r;
            if ((flags & 8) && row == 0 && col < N - 1) continue;
            if (flags & 32) {
              int pk = __builtin_amdgcn_cvt_pk_fp8_f32(v[r], v[r], 0, false);
              ((unsigned char*)C)[(long)z * sCz + (long)row * ldc + col] = (unsigned char)(pk & 0xff);
            } else if (flags & 2) {
              ((bf16*)C)[(long)z * sCz + (long)row * ldc + col] = (bf16)v[r];
            } else {
              ((float*)C)[(long)z * sCz + (long)row * ldc + col] = v[r];
            }
          }
        }
      }
  }
}

// ---------------- 64x64-tile GEMM (QKV only: panels L2-resident, occupancy-bound) ----------------
template <int SWAP>
__global__ __launch_bounds__(256) void gemm64_k(
    const bf16* __restrict__ A, long sAz, int lda,
    const bf16* __restrict__ B, long sBz, int ldb,
    void* __restrict__ C, long sCz, int ldc,
    const float* __restrict__ bias, long sBiasZ, int flags,
    int M, int N, int K, bf16* __restrict__ Ct)
{
  __shared__ bf16 lsA[64 * 32];
  __shared__ bf16 lsB[64 * 32];
  const int z = blockIdx.z;
  A += (long)z * sAz;
  B += (long)z * sBz;
  const int m0 = blockIdx.y * 64, n0 = blockIdx.x * 64;
  const int tid = threadIdx.x;
  const int lane = tid & 63, w = tid >> 6;
  const int wr = (w >> 1) * 32, wc = (w & 1) * 32;
  const int r15 = lane & 15, kg = lane >> 4;
  const int srow = tid >> 2, scol = (tid & 3) * 8;

  const bf16* Ag = A + (long)(m0 + srow) * lda + scol;
  const bf16* Bg = B + (long)(n0 + srow) * ldb + scol;
  bf16* La = &lsA[srow * 32 + scol];
  bf16* Lb = &lsB[srow * 32 + scol];

  f32x4 acc[2][2] = {};
  for (int k0 = 0; k0 < K; k0 += 32) {
    gload16(Ag + k0, La);
    gload16(Bg + k0, Lb);
    __syncthreads();
    bf16x8 af[2], bfr[2];
#pragma unroll
    for (int mi = 0; mi < 2; ++mi) af[mi] = *(const bf16x8*)&lsA[(wr + mi * 16 + r15) * 32 + kg * 8];
#pragma unroll
    for (int ni = 0; ni < 2; ++ni) bfr[ni] = *(const bf16x8*)&lsB[(wc + ni * 16 + r15) * 32 + kg * 8];
    __builtin_amdgcn_s_setprio(1);
#pragma unroll
    for (int mi = 0; mi < 2; ++mi)
#pragma unroll
      for (int ni = 0; ni < 2; ++ni) {
        if (SWAP)
          acc[mi][ni] = __builtin_amdgcn_mfma_f32_16x16x32_bf16(bfr[ni], af[mi], acc[mi][ni], 0, 0, 0);
        else
          acc[mi][ni] = __builtin_amdgcn_mfma_f32_16x16x32_bf16(af[mi], bfr[ni], acc[mi][ni], 0, 0, 0);
      }
    __builtin_amdgcn_s_setprio(0);
    __syncthreads();
  }
  const float* bz = bias ? bias + (long)z * sBiasZ : nullptr;
  const float scl = ((flags & 4) && z == 0) ? CST : 1.f;

#pragma unroll
  for (int mi = 0; mi < 2; ++mi)
#pragma unroll
    for (int ni = 0; ni < 2; ++ni) {
      int col = n0 + wc + ni * 16 + r15;
      float bv = bz ? bz[col] : 0.f;
      float v[4];
#pragma unroll
      for (int r = 0; r < 4; ++r) {
        v[r] = (acc[mi][ni][r] + bv) * scl;
        if (flags & 1) v[r] = fmaxf(v[r], 0.f);
      }
      int rowb = m0 + wr + mi * 16 + kg * 4;
      if ((flags & 16) && z == 2) {
        bf16x4 o = { (bf16)v[0], (bf16)v[1], (bf16)v[2], (bf16)v[3] };
        *(bf16x4*)&Ct[(long)col * M + rowb] = o;
      } else {
#pragma unroll
        for (int r = 0; r < 4; ++r) {
          int row = rowb + r;
          if (flags & 2) ((bf16*)C)[(long)z * sCz + (long)row * ldc + col] = (bf16)v[r];
          else           ((float*)C)[(long)z * sCz + (long)row * ldc + col] = v[r];
        }
      }
    }
}

// ---------------- fused prep: x0 conv / Er conv / zdiag(fp8) / bias pack / weight transposes ----------------
__global__ __launch_bounds__(256) void prep_k(
    const float* __restrict__ src, const float* __restrict__ Er,
    const float* __restrict__ Wq, const float* __restrict__ Wk, const float* __restrict__ Wv,
    const float* __restrict__ W1, const float* __restrict__ W2,
    const float* __restrict__ bq, const float* __restrict__ bk, const float* __restrict__ bv,
    bf16* __restrict__ x0b, bf16* __restrict__ erS, unsigned char* __restrict__ srel,
    float* __restrict__ bqkv,
    bf16* __restrict__ wqkvT, bf16* __restrict__ w1T, bf16* __restrict__ w2T)
{
  __shared__ float t[32][33];
  const int bid = blockIdx.x, tid = threadIdx.x;
  if (bid < 4096) {
    long i = (long)bid * 256 + tid;
    int s2 = (int)(i >> 9), d = (int)(i & 511);
    x0b[i] = (bf16)src[(long)s2 * (2 * DMODEL) + d];
    return;
  }
  int b1_ = bid - 4096;
  if (b1_ < 512) {
    long i = (long)b1_ * 256 + tid;
    erS[i] = (bf16)Er[(long)(MAXLEN - S) * DH + i];
    return;
  }
  b1_ -= 512;
  if (b1_ < 64) {
    int i = b1_ * 256 + tid;
    if (i < NH * (S - 1)) {
      int h = i / (S - 1), rg = i - h * (S - 1);
      srel[(long)h * S * S + (long)rg * (S + 1) + 1] = 0;  // fp8 zero
    }
    return;
  }
  b1_ -= 64;
  if (b1_ < 6) {
    int ti = b1_ * 256 + tid;
    bqkv[ti] = ti < 512 ? bq[ti] : (ti < 1024 ? bk[ti - 512] : bv[ti - 1024]);
    return;
  }
  b1_ -= 6;
  const float* in;
  bf16* out;
  int R, Cn, bx, by;
  if (b1_ < 768) {
    int z = b1_ >> 8, rem = b1_ & 255;
    in = z == 0 ? Wq : (z == 1 ? Wk : Wv);
    out = wqkvT + (long)z * DMODEL * DMODEL;
    R = DMODEL; Cn = DMODEL; bx = rem & 15; by = rem >> 4;
  } else if (b1_ < 768 + 1024) {
    int rem = b1_ - 768;
    in = W1; out = w1T; R = DMODEL; Cn = DFF; bx = rem & 63; by = rem >> 6;
  } else {
    int rem = b1_ - 1792;
    in = W2; out = w2T; R = DFF; Cn = DMODEL; bx = rem & 15; by = rem >> 4;
  }
  int c0 = bx * 32, r0 = by * 32, tx = tid & 31, ty = tid >> 5;
#pragma unroll
  for (int i = 0; i < 32; i += 8) t[ty + i][tx] = in[(long)(r0 + ty + i) * Cn + c0 + tx];
  __syncthreads();
#pragma unroll
  for (int i = 0; i < 32; i += 8) out[(long)(c0 + ty + i) * R + r0 + tx] = (bf16)t[tx][ty + i];
}

// ---------------- fused attention v9 (r15, fp8 srel tile; measured best) ----------------
__global__ __launch_bounds__(256, 5) void attn_k(
    const bf16* __restrict__ qg, const bf16* __restrict__ kgl, const bf16* __restrict__ vtg,
    const unsigned char* __restrict__ srel,
    bf16* __restrict__ pO, float* __restrict__ pM, float* __restrict__ pL)
{
  __shared__ bf16 Kl[64 * 72];            // K tile [c][k]
  __shared__ bf16 Vl[64 * 72];            // V^T tile [d][c]
  __shared__ unsigned char SPb[64 * 72];  // fp8 Srel tile [q][c]
  __shared__ bf16 Pl[4][16 * 72];         // per-wave P
  const int bx = blockIdx.x, h = blockIdx.y;
  const int rb = bx >> 3, sp = bx & 7;
  const int r0 = rb * 64;
  const int cb = sp * CW;
  const int tid = threadIdx.x, lane = tid & 63, w = tid >> 6;
  const int r15 = lane & 15, g = lane >> 4;
  const long hb = (long)h * S * S;

  bf16x8 qf0, qf1;
  {
    const bf16* qrow = qg + (long)(r0 + w * 16 + r15) * DMODEL + h * DH;
    qf0 = *(const bf16x8*)&qrow[g * 8];
    qf1 = *(const bf16x8*)&qrow[32 + g * 8];
  }
  f32x4 Oacc[4] = {};
  float m2 = -1e30f, l2 = 0.f;

  const int myrow = w * 16 + r15;
  const int rg = r0 + myrow;

  const int kRow = tid >> 3, kCh = (tid & 7) * 8;
  const int sRow = tid >> 2, sCh = (tid & 3) * 16;
  bf16x8 kf0, kf1, vf0, vf1;
  u64x2 sf;

  auto LOADR = [&](int c0) {
    kf0 = *(const bf16x8*)&kgl[(long)(c0 + kRow) * DMODEL + h * DH + kCh];
    kf1 = *(const bf16x8*)&kgl[(long)(c0 + kRow + 32) * DMODEL + h * DH + kCh];
    vf0 = *(const bf16x8*)&vtg[(long)(h * DH + kRow) * S + c0 + kCh];
    vf1 = *(const bf16x8*)&vtg[(long)(h * DH + kRow + 32) * S + c0 + kCh];
    sf = *(const u64x2*)&srel[hb + (long)(r0 + sRow) * S + c0 + sCh];
  };
  auto STORE = [&]() {
    *(bf16x8*)&Kl[kRow * 72 + kCh] = kf0;
    *(bf16x8*)&Kl[(kRow + 32) * 72 + kCh] = kf1;
    *(bf16x8*)&Vl[kRow * 72 + kCh] = vf0;
    *(bf16x8*)&Vl[(kRow + 32) * 72 + kCh] = vf1;
    *(unsigned long*)&SPb[sRow * 72 + sCh] = sf.x;
    *(unsigned long*)&SPb[sRow * 72 + sCh + 8] = sf.y;
  };

  LOADR(cb);
#pragma unroll
  for (int t = 0; t < CW / BC; ++t) {
    __syncthreads();
    STORE();
    if (t + 1 < CW / BC) LOADR(cb + (t + 1) * BC);
    __syncthreads();

    f32x4 sc[4];
    __builtin_amdgcn_s_setprio(1);
#pragma unroll
    for (int ni = 0; ni < 4; ++ni) {
      bf16x8 k0f = *(const bf16x8*)&Kl[(ni * 16 + r15) * 72 + g * 8];
      bf16x8 k1f = *(const bf16x8*)&Kl[(ni * 16 + r15) * 72 + 32 + g * 8];
      f32x4 a = {};
      a = __builtin_amdgcn_mfma_f32_16x16x32_bf16(k0f, qf0, a, 0, 0, 0);
      a = __builtin_amdgcn_mfma_f32_16x16x32_bf16(k1f, qf1, a, 0, 0, 0);
      sc[ni] = a;
    }
    __builtin_amdgcn_s_setprio(0);

    const unsigned char* Sw = &SPb[myrow * 72];
#pragma unroll
    for (int ni = 0; ni < 4; ++ni) {
      unsigned int u = *(const unsigned int*)&Sw[ni * 16 + 4 * g];
      sc[ni][0] += __builtin_amdgcn_cvt_f32_fp8(u, 0);
      sc[ni][1] += __builtin_amdgcn_cvt_f32_fp8(u, 1);
      sc[ni][2] += __builtin_amdgcn_cvt_f32_fp8(u, 2);
      sc[ni][3] += __builtin_amdgcn_cvt_f32_fp8(u, 3);
    }

    float tmax = sc[0][0];
#pragma unroll
    for (int ni = 0; ni < 4; ++ni)
#pragma unroll
      for (int r = 0; r < 4; ++r) tmax = fmaxf(tmax, sc[ni][r]);
    tmax = fmaxf(tmax, __shfl_xor(tmax, 16));
    tmax = fmaxf(tmax, __shfl_xor(tmax, 32));

    float mn = fmaxf(m2, tmax);
    float al = exp2f(m2 - mn);
    m2 = mn;
    float tsum = 0.f;
#pragma unroll
    for (int ni = 0; ni < 4; ++ni)
#pragma unroll
      for (int r = 0; r < 4; ++r) {
        float p = exp2f(sc[ni][r] - m2);
        sc[ni][r] = p;
        tsum += p;
      }
    tsum += __shfl_xor(tsum, 16);
    tsum += __shfl_xor(tsum, 32);
    l2 = l2 * al + tsum;

#pragma unroll
    for (int no = 0; no < 4; ++no)
#pragma unroll
      for (int r = 0; r < 4; ++r) Oacc[no][r] *= al;

    bf16* Pw = Pl[w];
#pragma unroll
    for (int ni = 0; ni < 4; ++ni) {
      bf16x4 pv = { (bf16)sc[ni][0], (bf16)sc[ni][1], (bf16)sc[ni][2], (bf16)sc[ni][3] };
      *(bf16x4*)&Pw[r15 * 72 + ni * 16 + 4 * g] = pv;
    }

    __builtin_amdgcn_s_setprio(1);
#pragma unroll
    for (int kc = 0; kc < 2; ++kc) {
      bf16x8 pf = *(const bf16x8*)&Pw[r15 * 72 + kc * 32 + g * 8];
#pragma unroll
      for (int no = 0; no < 4; ++no) {
        bf16x8 av = *(const bf16x8*)&Vl[(no * 16 + r15) * 72 + kc * 32 + g * 8];
        Oacc[no] = __builtin_amdgcn_mfma_f32_16x16x32_bf16(av, pf, Oacc[no], 0, 0, 0);
      }
    }
    __builtin_amdgcn_s_setprio(0);
  }

  const long ob = ((long)sp * NH + h) * S * DH;
  const long qrow_g = r0 + w * 16 + r15;
#pragma unroll
  for (int no = 0; no < 4; ++no) {
    bf16x4 ov = { (bf16)Oacc[no][0], (bf16)Oacc[no][1], (bf16)Oacc[no][2], (bf16)Oacc[no][3] };
    *(bf16x4*)&pO[ob + qrow_g * DH + no * 16 + 4 * g] = ov;
  }
  if (g == 0) {
    const long sb = ((long)sp * NH + h) * S;
    pM[sb + rg] = m2;
    pL[sb + rg] = l2;
  }
}

// ---------------- layernorm helpers ----------------
__device__ __forceinline__ float blk_sum(float v, float* red) {
  for (int o = 32; o; o >>= 1) v += __shfl_xor(v, o);
  int tid = threadIdx.x;
  if ((tid & 63) == 0) red[tid >> 6] = v;
  __syncthreads();
  v = red[0] + red[1] + red[2] + red[3];
  __syncthreads();
  return v;
}

// ---------------- fused merge + LN1 ----------------
__global__ __launch_bounds__(256) void lnm1_k(
    const float* __restrict__ src, const bf16* __restrict__ pO,
    const float* __restrict__ pM, const float* __restrict__ pL,
    const float* __restrict__ g, const float* __restrict__ be, bf16* __restrict__ y)
{
  __shared__ float red[4];
  const int s2 = blockIdx.x, tid = threadIdx.x;
  float sa[2];
#pragma unroll
  for (int half = 0; half < 2; ++half) {
    int col = tid + half * 256;
    int h = col >> 6, d = col & 63;
    long i0 = (long)h * S + s2;
    float mm = -1e30f, ms[NSP];
#pragma unroll
    for (int s = 0; s < NSP; ++s) { ms[s] = pM[(long)s * NH * S + i0]; mm = fmaxf(mm, ms[s]); }
    float num = 0.f, den = 0.f;
#pragma unroll
    for (int s = 0; s < NSP; ++s) {
      float e = exp2f(ms[s] - mm);
      den += pL[(long)s * NH * S + i0] * e;
      num += (float)pO[(long)s * NH * S * DH + i0 * DH + d] * e;
    }
    sa[half] = num / den;
  }
#pragma unroll
  for (int b = 0; b < 2; ++b) {
    const float* xs = src + (long)s2 * (2 * DMODEL) + b * DMODEL;
    float a0 = xs[tid] + sa[0];
    float a1 = xs[tid + 256] + sa[1];
    float sum = blk_sum(a0 + a1, red);
    float sq  = blk_sum(a0 * a0 + a1 * a1, red);
    float mu = sum * (1.f / DMODEL);
    float var = sq * (1.f / DMODEL) - mu * mu;
    float rs = rsqrtf(var + LN_EPS);
    long ro = ((long)b * S + s2) * DMODEL;
    y[ro + tid]       = (bf16)((a0 - mu) * rs * g[tid] + be[tid]);
    y[ro + tid + 256] = (bf16)((a1 - mu) * rs * g[tid + 256] + be[tid + 256]);
  }
}

// out = LN( y + sum_4(pFF) + b2 ) ; pFF are bf16 split-K partials
__global__ __launch_bounds__(256) void ln2_k(
    const bf16* __restrict__ y, const bf16* __restrict__ pFF, long pStride,
    const float* __restrict__ b2,
    const float* __restrict__ g, const float* __restrict__ be, float* __restrict__ out)
{
  __shared__ float red[4];
  const int row = blockIdx.x;
  const int b = row >> 11, s2 = row & 2047;
  const int tid = threadIdx.x;
  long i0 = (long)row * DMODEL + tid;
  long i1 = i0 + 256;
  float f0 = (float)pFF[i0] + (float)pFF[i0 + pStride] + (float)pFF[i0 + 2 * pStride] +
             (float)pFF[i0 + 3 * pStride] + b2[tid];
  float f1 = (float)pFF[i1] + (float)pFF[i1 + pStride] + (float)pFF[i1 + 2 * pStride] +
             (float)pFF[i1 + 3 * pStride] + b2[tid + 256];
  float a0 = (float)y[i0] + f0;
  float a1 = (float)y[i1] + f1;
  float sum = blk_sum(a0 + a1, red);
  float sq  = blk_sum(a0 * a0 + a1 * a1, red);
  float mu = sum * (1.f / DMODEL);
  float var = sq * (1.f / DMODEL) - mu * mu;
  float rs = rsqrtf(var + LN_EPS);
  float* o = out + (long)s2 * (2 * DMODEL) + b * DMODEL;
  o[tid]       = (a0 - mu) * rs * g[tid] + be[tid];
  o[tid + 256] = (a1 - mu) * rs * g[tid + 256] + be[tid + 256];
}

// ---------------- host launch ----------------
extern "C" void kernel_launch(void* const* d_in, const int* in_sizes, int n_in,
                              void* d_out, int out_size, void* d_ws, size_t ws_size,
                              hipStream_t stream)
{
  const float* src = (const float*)d_in[0];
  const float* Wq  = (const float*)d_in[1];
  const float* bq  = (const float*)d_in[2];
  const float* Wk  = (const float*)d_in[3];
  const float* bk  = (const float*)d_in[4];
  const float* Wv  = (const float*)d_in[5];
  const float* bv  = (const float*)d_in[6];
  const float* Er  = (const float*)d_in[7];
  const float* W1  = (const float*)d_in[8];
  const float* b1  = (const float*)d_in[9];
  const float* W2  = (const float*)d_in[10];
  const float* b2  = (const float*)d_in[11];
  const float* g1  = (const float*)d_in[12];
  const float* be1 = (const float*)d_in[13];
  const float* g2  = (const float*)d_in[14];
  const float* be2 = (const float*)d_in[15];

  char* wp = (char*)d_ws;
  auto alloc = [&](size_t bytes) { char* p = wp; wp += (bytes + 255) & ~(size_t)255; return p; };

  bf16* x0b   = (bf16*)alloc((size_t)S * DMODEL * 2);
  bf16* wqkvT = (bf16*)alloc((size_t)3 * DMODEL * DMODEL * 2);
  float* bqkv = (float*)alloc((size_t)3 * DMODEL * 4);
  bf16* w1T   = (bf16*)alloc((size_t)DFF * DMODEL * 2);
  bf16* w2T   = (bf16*)alloc((size_t)DMODEL * DFF * 2);
  bf16* erS   = (bf16*)alloc((size_t)S * DH * 2);
  bf16* qkvb  = (bf16*)alloc((size_t)3 * S * DMODEL * 2);
  bf16* vt    = (bf16*)alloc((size_t)DMODEL * S * 2);
  unsigned char* srel = (unsigned char*)alloc((size_t)NH * S * S);
  bf16* pO    = (bf16*)alloc((size_t)NSP * NH * S * DH * 2);
  float* pM   = (float*)alloc((size_t)NSP * NH * S * 4);
  float* pL   = (float*)alloc((size_t)NSP * NH * S * 4);
  bf16* yb    = (bf16*)alloc((size_t)2 * S * DMODEL * 2);
  bf16* h1    = (bf16*)alloc((size_t)2 * S * DFF * 2);
  bf16* pFF   = (bf16*)alloc((size_t)4 * 2 * S * DMODEL * 2);

  const long MN2 = (long)2 * S * DMODEL;

  // all prep in one launch
  prep_k<<<7494, 256, 0, stream>>>(src, Er, Wq, Wk, Wv, W1, W2, bq, bk, bv,
                                   x0b, erS, srel, bqkv, wqkvT, w1T, w2T);

  // QKV (batch 0 only), 64x64 tiles -> 768 blocks; z==0 (Q) pre-scaled; V transposed
  gemm64_k<0><<<dim3(DMODEL / 64, S / 64, 3), 256, 0, stream>>>(
      x0b, 0, DMODEL, wqkvT, (long)DMODEL * DMODEL, DMODEL,
      qkvb, (long)S * DMODEL, DMODEL, bqkv, DMODEL, 2 | 4 | 16, S, DMODEL, DMODEL, vt);

  const bf16* qb = qkvb;
  const bf16* kb = qkvb + (long)S * DMODEL;

  // Srel materialized directly as fp8 (128x128 tiles, write-bound)
  gemm_k<0><<<dim3(16, 16, 8), 256, 0, stream>>>(
      qb, DH, DMODEL, erS, 0, DH, (void*)(srel - (S - 1)), (long)S * S, S + 1,
      nullptr, 0, 8 | 32, S, S, DH, nullptr);

  // fused attention (r15 best)
  attn_k<<<dim3(32 * NSP, NH), 256, 0, stream>>>(qb, kb, vt, srel, pO, pM, pL);

  // fused merge + LN1 -> y (bf16)
  lnm1_k<<<S, 256, 0, stream>>>(src, pO, pM, pL, g1, be1, yb);

  // FFN1: 128x128 tiles (r15 config — better panel reuse)
  gemm_k<1><<<dim3(DFF / 128, (2 * S) / 128, 1), 256, 0, stream>>>(
      yb, 0, DMODEL, w1T, 0, DMODEL, h1, 0, DFF, b1, 0, 3, 2 * S, DFF, DMODEL, nullptr);

  // FFN2 split-K=4: 128x128 tiles (r15 config)
  gemm_k<1><<<dim3(DMODEL / 128, (2 * S) / 128, 4), 256, 0, stream>>>(
      h1, 512, DFF, w2T, 512, DFF, pFF, MN2, DMODEL, nullptr, 0, 2, 2 * S, DMODEL, 512, nullptr);

  // LN2 (+partial-sum +b2) -> out
  ln2_k<<<2 * S, 256, 0, stream>>>(yb, pFF, MN2, b2, g2, be2, (float*)d_out);
}